// Round 1
// baseline (651.021 us; speedup 1.0000x reference)
//
#include <hip/hip_runtime.h>

#define NN 8192
#define DD 64
#define BM 32

typedef _Float16 f16;
typedef _Float16 f16x8 __attribute__((ext_vector_type(8)));
typedef float f32x4 __attribute__((ext_vector_type(4)));

// ---------------------------------------------------------------------------
// prep: dinv[i] = rsqrt(degree[i]+1); xsT[c][i] = f16(x[i][c] * dinv[i])
// xsT is the transposed, degree-scaled feature matrix (B operand of pass 1).
// ---------------------------------------------------------------------------
__global__ __launch_bounds__(256) void prep_kernel(
    const float* __restrict__ x, const float* __restrict__ degree,
    f16* __restrict__ xsT, float* __restrict__ dinv) {
  int i = blockIdx.x * blockDim.x + threadIdx.x;
  if (i >= NN) return;
  float d = rsqrtf(degree[i] + 1.0f);
  dinv[i] = d;
  const float4* xr = (const float4*)(x + (size_t)i * DD);
#pragma unroll
  for (int c4 = 0; c4 < 16; ++c4) {
    float4 v = xr[c4];
    int c = c4 * 4;
    // per-wave: consecutive i at fixed c -> contiguous 2B*64 stores (coalesced)
    xsT[(size_t)(c + 0) * NN + i] = (f16)(v.x * d);
    xsT[(size_t)(c + 1) * NN + i] = (f16)(v.y * d);
    xsT[(size_t)(c + 2) * NN + i] = (f16)(v.z * d);
    xsT[(size_t)(c + 3) * NN + i] = (f16)(v.w * d);
  }
}

// ---------------------------------------------------------------------------
// agg_kernel: C = adj[rows rg0..rg0+31][:] @ BT^T   (BT is [64][8192] f16)
// epilogue fuses: row-scale by dinv, @W + bias, then
//   FIRST:  ReLU, scale by dinv, store transposed f16 (next layer's B)
//   !FIRST: + x residual, LayerNorm * gamma + beta -> out (fp32)
// A16: read adj from f16 workspace copy. WRITE16: write f16 copy while converting.
// ---------------------------------------------------------------------------
template <bool A16, bool FIRST, bool WRITE16>
__global__ __launch_bounds__(256) void agg_kernel(
    const float* __restrict__ adjf, const f16* __restrict__ adjh,
    f16* __restrict__ adjh_out, const f16* __restrict__ BT,
    const float* __restrict__ dinv, const float* __restrict__ W,
    const float* __restrict__ bias, const float* __restrict__ xres,
    const float* __restrict__ gamma, const float* __restrict__ beta,
    f16* __restrict__ h1sT, float* __restrict__ out) {
  __shared__ __align__(16) float Wlds[DD * DD];
  __shared__ __align__(16) float Cs[BM][DD + 1];
  __shared__ __align__(16) f16 hT[DD][BM + 2];

  const int tid = threadIdx.x;
  const int wv = tid >> 6;  // wave 0..3
  const int l = tid & 63;
  const int rg0 = blockIdx.x * BM;

  // stage W (64x64 fp32) into LDS; consumed after the main-loop barrier
  for (int idx = tid * 4; idx < DD * DD; idx += 1024)
    *(float4*)&Wlds[idx] = *(const float4*)&W[idx];

  // wave tiling: rows 16*(wv&1).. (M=16), cols 32*(wv>>1).. (two 16-col frags)
  const int rowA = 16 * (wv & 1) + (l & 15);
  const int kb = 8 * (l >> 4);  // 8 contiguous k per lane
  const int colB0 = 32 * (wv >> 1);

  f32x4 acc0 = {0.f, 0.f, 0.f, 0.f};
  f32x4 acc1 = {0.f, 0.f, 0.f, 0.f};

  const size_t arow = (size_t)(rg0 + rowA) * NN + kb;
  const f16* bp0 = BT + (size_t)(colB0 + (l & 15)) * NN + kb;
  const f16* bp1 = bp0 + (size_t)16 * NN;

  if constexpr (A16) {
#pragma unroll 8
    for (int k0 = 0; k0 < NN; k0 += 32) {
      f16x8 a = *(const f16x8*)(adjh + arow + k0);
      f16x8 b0 = *(const f16x8*)(bp0 + k0);
      f16x8 b1 = *(const f16x8*)(bp1 + k0);
      acc0 = __builtin_amdgcn_mfma_f32_16x16x32_f16(a, b0, acc0, 0, 0, 0);
      acc1 = __builtin_amdgcn_mfma_f32_16x16x32_f16(a, b1, acc1, 0, 0, 0);
    }
  } else {
#pragma unroll 4
    for (int k0 = 0; k0 < NN; k0 += 32) {
      // nontemporal: streamed-once fp32 adj must not evict the f16 copy in L3
      f32x4 a0 = __builtin_nontemporal_load((const f32x4*)(adjf + arow + k0));
      f32x4 a1 = __builtin_nontemporal_load((const f32x4*)(adjf + arow + k0) + 1);
      f16x8 a;
      a[0] = (f16)a0[0]; a[1] = (f16)a0[1]; a[2] = (f16)a0[2]; a[3] = (f16)a0[3];
      a[4] = (f16)a1[0]; a[5] = (f16)a1[1]; a[6] = (f16)a1[2]; a[7] = (f16)a1[3];
      if constexpr (WRITE16) {
        if ((wv >> 1) == 0) *(f16x8*)(adjh_out + arow + k0) = a;  // each elem once
      }
      f16x8 b0 = *(const f16x8*)(bp0 + k0);
      f16x8 b1 = *(const f16x8*)(bp1 + k0);
      acc0 = __builtin_amdgcn_mfma_f32_16x16x32_f16(a, b0, acc0, 0, 0, 0);
      acc1 = __builtin_amdgcn_mfma_f32_16x16x32_f16(a, b1, acc1, 0, 0, 0);
    }
  }

  // C frags -> LDS. C layout: col = lane&15, row = 4*(lane>>4)+reg (HW-verified)
  {
    const int r0 = 16 * (wv & 1) + 4 * (l >> 4);
    const int c = colB0 + (l & 15);
#pragma unroll
    for (int j = 0; j < 4; ++j) Cs[r0 + j][c] = acc0[j];
#pragma unroll
    for (int j = 0; j < 4; ++j) Cs[r0 + j][c + 16] = acc1[j];
  }
  __syncthreads();

  // epilogue: thread owns (row r, 8 cols c0..c0+7);  h = dr*(C@W) + b
  const int r = tid >> 3;
  const int c0 = (tid & 7) * 8;
  const float dr = dinv[rg0 + r];
  float av[8];
#pragma unroll
  for (int j = 0; j < 8; ++j) av[j] = 0.f;
  for (int k = 0; k < DD; ++k) {
    float cv = Cs[r][k];
#pragma unroll
    for (int j = 0; j < 8; ++j) av[j] += cv * Wlds[k * DD + c0 + j];
  }

  if constexpr (FIRST) {
#pragma unroll
    for (int j = 0; j < 8; ++j) {
      float h = fmaxf(dr * av[j] + bias[c0 + j], 0.f);
      hT[c0 + j][r] = (f16)(h * dr);  // pre-scale for next layer's B operand
    }
    __syncthreads();
    // cooperative transposed coalesced store: h1sT[col][rg0..rg0+31]
    const int col = tid >> 2;
    const int rp = (tid & 3) * 8;
    f16x8 v;
#pragma unroll
    for (int j = 0; j < 8; ++j) v[j] = hT[col][rp + j];
    *(f16x8*)(h1sT + (size_t)col * NN + rg0 + rp) = v;
  } else {
    float hv[8];
    const float* xp = xres + (size_t)(rg0 + r) * DD + c0;
    f32x4 xa = *(const f32x4*)xp;
    f32x4 xb = *(const f32x4*)(xp + 4);
#pragma unroll
    for (int j = 0; j < 4; ++j) hv[j] = dr * av[j] + bias[c0 + j] + xa[j];
#pragma unroll
    for (int j = 0; j < 4; ++j) hv[4 + j] = dr * av[4 + j] + bias[c0 + 4 + j] + xb[j];
    // LayerNorm over the 64-wide row: 8 threads/row, contiguous 8-lane group
    float s = 0.f, sq = 0.f;
#pragma unroll
    for (int j = 0; j < 8; ++j) { s += hv[j]; sq += hv[j] * hv[j]; }
    s += __shfl_xor(s, 1); s += __shfl_xor(s, 2); s += __shfl_xor(s, 4);
    sq += __shfl_xor(sq, 1); sq += __shfl_xor(sq, 2); sq += __shfl_xor(sq, 4);
    const float mean = s * (1.f / 64.f);
    const float var = sq * (1.f / 64.f) - mean * mean;
    const float rstd = rsqrtf(var + 1e-5f);
    f32x4 o0, o1;
#pragma unroll
    for (int j = 0; j < 4; ++j)
      o0[j] = (hv[j] - mean) * rstd * gamma[c0 + j] + beta[c0 + j];
#pragma unroll
    for (int j = 0; j < 4; ++j)
      o1[j] = (hv[4 + j] - mean) * rstd * gamma[c0 + 4 + j] + beta[c0 + 4 + j];
    float* op = out + (size_t)(rg0 + r) * DD + c0;
    *(f32x4*)op = o0;
    *(f32x4*)(op + 4) = o1;
  }
}

extern "C" void kernel_launch(void* const* d_in, const int* in_sizes, int n_in,
                              void* d_out, int out_size, void* d_ws, size_t ws_size,
                              hipStream_t stream) {
  (void)in_sizes; (void)n_in; (void)out_size;
  const float* x = (const float*)d_in[0];
  const float* adj = (const float*)d_in[1];
  const float* degree = (const float*)d_in[2];
  const float* W0 = (const float*)d_in[3];
  const float* b0 = (const float*)d_in[4];
  const float* W1 = (const float*)d_in[5];
  const float* b1 = (const float*)d_in[6];
  const float* gamma = (const float*)d_in[7];
  const float* beta = (const float*)d_in[8];
  float* out = (float*)d_out;

  char* ws = (char*)d_ws;
  size_t off = 0;
  f16* xsT = (f16*)(ws + off);  off += (size_t)DD * NN * sizeof(f16);
  f16* h1sT = (f16*)(ws + off); off += (size_t)DD * NN * sizeof(f16);
  float* dinv = (float*)(ws + off); off += (size_t)NN * sizeof(float);
  off = (off + 255) & ~(size_t)255;
  const size_t adj16_bytes = (size_t)NN * NN * sizeof(f16);
  const bool use16 = (ws_size >= off + adj16_bytes);
  f16* adj16 = (f16*)(ws + off);

  prep_kernel<<<NN / 256, 256, 0, stream>>>(x, degree, xsT, dinv);
  if (use16) {
    agg_kernel<false, true, true><<<NN / BM, 256, 0, stream>>>(
        adj, nullptr, adj16, xsT, dinv, W0, b0, nullptr, nullptr, nullptr,
        h1sT, nullptr);
    agg_kernel<true, false, false><<<NN / BM, 256, 0, stream>>>(
        nullptr, adj16, nullptr, h1sT, dinv, W1, b1, x, gamma, beta,
        nullptr, out);
  } else {
    agg_kernel<false, true, false><<<NN / BM, 256, 0, stream>>>(
        adj, nullptr, nullptr, xsT, dinv, W0, b0, nullptr, nullptr, nullptr,
        h1sT, nullptr);
    agg_kernel<false, false, false><<<NN / BM, 256, 0, stream>>>(
        adj, nullptr, nullptr, h1sT, dinv, W1, b1, x, gamma, beta,
        nullptr, out);
  }
}

// Round 3
// 615.136 us; speedup vs baseline: 1.0583x; 1.0583x over previous
//
#include <hip/hip_runtime.h>

#define NN 8192
#define DD 64
#define BM 32
#define KSPLIT 4
#define KCHUNK (NN / KSPLIT)  // 2048 k per block

typedef _Float16 f16;
typedef _Float16 f16x8 __attribute__((ext_vector_type(8)));
typedef float f32x4 __attribute__((ext_vector_type(4)));

// ---------------------------------------------------------------------------
// prep: dinv[i] = rsqrt(degree[i]+1); xsT[c][i] = f16(x[i][c] * dinv[i])
// ---------------------------------------------------------------------------
__global__ __launch_bounds__(256) void prep_kernel(
    const float* __restrict__ x, const float* __restrict__ degree,
    f16* __restrict__ xsT, float* __restrict__ dinv) {
  int i = blockIdx.x * blockDim.x + threadIdx.x;
  if (i >= NN) return;
  float d = rsqrtf(degree[i] + 1.0f);
  dinv[i] = d;
  const float4* xr = (const float4*)(x + (size_t)i * DD);
#pragma unroll
  for (int c4 = 0; c4 < 16; ++c4) {
    float4 v = xr[c4];
    int c = c4 * 4;
    xsT[(size_t)(c + 0) * NN + i] = (f16)(v.x * d);
    xsT[(size_t)(c + 1) * NN + i] = (f16)(v.y * d);
    xsT[(size_t)(c + 2) * NN + i] = (f16)(v.z * d);
    xsT[(size_t)(c + 3) * NN + i] = (f16)(v.w * d);
  }
}

// ---------------------------------------------------------------------------
// mm_kernel: partial C = adj[rows rg0..rg0+31][ks0..ks0+KCHUNK) @ BT^T
// grid = (NN/BM, KSPLIT).  Writes fp32 partial tile to Cpart[ksp][N][64].
// A16: read f16 adj copy.  WRITE16: write f16 copy while converting fp32.
// No LDS; 16 waves/CU at grid 1024 -> latency hidden, HBM-bound.
// ---------------------------------------------------------------------------
template <bool A16, bool WRITE16>
__global__ __launch_bounds__(256, 8) void mm_kernel(
    const float* __restrict__ adjf, const f16* __restrict__ adjh,
    f16* __restrict__ adjh_out, const f16* __restrict__ BT,
    float* __restrict__ Cpart) {
  const int tid = threadIdx.x;
  const int wv = tid >> 6;
  const int l = tid & 63;
  const int rg0 = blockIdx.x * BM;
  const int ks0 = blockIdx.y * KCHUNK;

  // wave tiling: rows 16*(wv&1) (M=16), cols 32*(wv>>1) (two 16-col frags)
  const int rowA = 16 * (wv & 1) + (l & 15);
  const int kb = 8 * (l >> 4);  // 8 contiguous k per lane
  const int colB0 = 32 * (wv >> 1);

  f32x4 acc0 = {0.f, 0.f, 0.f, 0.f};
  f32x4 acc1 = {0.f, 0.f, 0.f, 0.f};

  const size_t arow = (size_t)(rg0 + rowA) * NN + ks0 + kb;
  const f16* bp0 = BT + (size_t)(colB0 + (l & 15)) * NN + ks0 + kb;
  const f16* bp1 = bp0 + (size_t)16 * NN;

  if constexpr (A16) {
#pragma unroll 8
    for (int k0 = 0; k0 < KCHUNK; k0 += 32) {
      f16x8 a = *(const f16x8*)(adjh + arow + k0);
      f16x8 b0 = *(const f16x8*)(bp0 + k0);
      f16x8 b1 = *(const f16x8*)(bp1 + k0);
      acc0 = __builtin_amdgcn_mfma_f32_16x16x32_f16(a, b0, acc0, 0, 0, 0);
      acc1 = __builtin_amdgcn_mfma_f32_16x16x32_f16(a, b1, acc1, 0, 0, 0);
    }
  } else {
#pragma unroll 4
    for (int k0 = 0; k0 < KCHUNK; k0 += 32) {
      // nontemporal: streamed-once fp32 adj must not evict f16 copy / B in L3
      f32x4 a0 = __builtin_nontemporal_load((const f32x4*)(adjf + arow + k0));
      f32x4 a1 = __builtin_nontemporal_load((const f32x4*)(adjf + arow + k0) + 1);
      f16x8 a;
      a[0] = (f16)a0[0]; a[1] = (f16)a0[1]; a[2] = (f16)a0[2]; a[3] = (f16)a0[3];
      a[4] = (f16)a1[0]; a[5] = (f16)a1[1]; a[6] = (f16)a1[2]; a[7] = (f16)a1[3];
      if constexpr (WRITE16) {
        if ((wv >> 1) == 0) *(f16x8*)(adjh_out + arow + k0) = a;  // each elem once
      }
      f16x8 b0 = *(const f16x8*)(bp0 + k0);
      f16x8 b1 = *(const f16x8*)(bp1 + k0);
      acc0 = __builtin_amdgcn_mfma_f32_16x16x32_f16(a, b0, acc0, 0, 0, 0);
      acc1 = __builtin_amdgcn_mfma_f32_16x16x32_f16(a, b1, acc1, 0, 0, 0);
    }
  }

  // direct partial store. C layout: col = lane&15, row = 4*(lane>>4)+reg.
  // For fixed j, lanes 0-15 / 16-31 each write one 64B-aligned 64B segment.
  float* cp = Cpart + ((size_t)blockIdx.y * NN + rg0 + 16 * (wv & 1) + 4 * (l >> 4)) * DD
              + colB0 + (l & 15);
#pragma unroll
  for (int j = 0; j < 4; ++j) {
    cp[(size_t)j * DD] = acc0[j];
    cp[(size_t)j * DD + 16] = acc1[j];
  }
}

// ---------------------------------------------------------------------------
// epi_kernel: sum KSPLIT partials -> C[32][64]; h = dr*(C@W)+b; then
//   FIRST:  ReLU, scale by dinv, store transposed f16 (next layer's B)
//   !FIRST: + x residual, LayerNorm * gamma + beta -> out (fp32)
// ---------------------------------------------------------------------------
template <bool FIRST>
__global__ __launch_bounds__(256) void epi_kernel(
    const float* __restrict__ Cpart, const float* __restrict__ dinv,
    const float* __restrict__ W, const float* __restrict__ bias,
    const float* __restrict__ xres, const float* __restrict__ gamma,
    const float* __restrict__ beta, f16* __restrict__ h1sT,
    float* __restrict__ out) {
  __shared__ __align__(16) float Wlds[DD * DD];
  __shared__ __align__(16) float Cs[BM][DD + 1];
  __shared__ __align__(16) f16 hT[DD][BM + 2];

  const int tid = threadIdx.x;
  const int rg0 = blockIdx.x * BM;

  for (int idx = tid * 4; idx < DD * DD; idx += 1024)
    *(float4*)&Wlds[idx] = *(const float4*)&W[idx];

  // sum partials: thread owns (row r, cols c0..c0+7)
  const int r = tid >> 3;
  const int c0 = (tid & 7) * 8;
  f32x4 s0 = {0.f, 0.f, 0.f, 0.f};
  f32x4 s1 = {0.f, 0.f, 0.f, 0.f};
#pragma unroll
  for (int ksp = 0; ksp < KSPLIT; ++ksp) {
    const float* p = Cpart + ((size_t)ksp * NN + rg0 + r) * DD + c0;
    s0 += *(const f32x4*)p;
    s1 += *(const f32x4*)(p + 4);
  }
#pragma unroll
  for (int j = 0; j < 4; ++j) { Cs[r][c0 + j] = s0[j]; Cs[r][c0 + 4 + j] = s1[j]; }
  __syncthreads();

  const float dr = dinv[rg0 + r];
  float av[8];
#pragma unroll
  for (int j = 0; j < 8; ++j) av[j] = 0.f;
  for (int k = 0; k < DD; ++k) {
    float cv = Cs[r][k];
#pragma unroll
    for (int j = 0; j < 8; ++j) av[j] += cv * Wlds[k * DD + c0 + j];
  }

  if constexpr (FIRST) {
#pragma unroll
    for (int j = 0; j < 8; ++j) {
      float h = fmaxf(dr * av[j] + bias[c0 + j], 0.f);
      hT[c0 + j][r] = (f16)(h * dr);  // pre-scale for next layer's B operand
    }
    __syncthreads();
    const int col = tid >> 2;
    const int rp = (tid & 3) * 8;
    f16x8 v;
#pragma unroll
    for (int j = 0; j < 8; ++j) v[j] = hT[col][rp + j];
    *(f16x8*)(h1sT + (size_t)col * NN + rg0 + rp) = v;
  } else {
    float hv[8];
    const float* xp = xres + (size_t)(rg0 + r) * DD + c0;
    f32x4 xa = *(const f32x4*)xp;
    f32x4 xb = *(const f32x4*)(xp + 4);
#pragma unroll
    for (int j = 0; j < 4; ++j) hv[j] = dr * av[j] + bias[c0 + j] + xa[j];
#pragma unroll
    for (int j = 0; j < 4; ++j) hv[4 + j] = dr * av[4 + j] + bias[c0 + 4 + j] + xb[j];
    float s = 0.f, sq = 0.f;
#pragma unroll
    for (int j = 0; j < 8; ++j) { s += hv[j]; sq += hv[j] * hv[j]; }
    s += __shfl_xor(s, 1); s += __shfl_xor(s, 2); s += __shfl_xor(s, 4);
    sq += __shfl_xor(sq, 1); sq += __shfl_xor(sq, 2); sq += __shfl_xor(sq, 4);
    const float mean = s * (1.f / 64.f);
    const float var = sq * (1.f / 64.f) - mean * mean;
    const float rstd = rsqrtf(var + 1e-5f);
    f32x4 o0, o1;
#pragma unroll
    for (int j = 0; j < 4; ++j)
      o0[j] = (hv[j] - mean) * rstd * gamma[c0 + j] + beta[c0 + j];
#pragma unroll
    for (int j = 0; j < 4; ++j)
      o1[j] = (hv[4 + j] - mean) * rstd * gamma[c0 + 4 + j] + beta[c0 + 4 + j];
    float* op = out + (size_t)(rg0 + r) * DD + c0;
    *(f32x4*)op = o0;
    *(f32x4*)(op + 4) = o1;
  }
}

extern "C" void kernel_launch(void* const* d_in, const int* in_sizes, int n_in,
                              void* d_out, int out_size, void* d_ws, size_t ws_size,
                              hipStream_t stream) {
  (void)in_sizes; (void)n_in; (void)out_size;
  const float* x = (const float*)d_in[0];
  const float* adj = (const float*)d_in[1];
  const float* degree = (const float*)d_in[2];
  const float* W0 = (const float*)d_in[3];
  const float* b0 = (const float*)d_in[4];
  const float* W1 = (const float*)d_in[5];
  const float* b1 = (const float*)d_in[6];
  const float* gamma = (const float*)d_in[7];
  const float* beta = (const float*)d_in[8];
  float* out = (float*)d_out;

  char* ws = (char*)d_ws;
  size_t off = 0;
  f16* xsT = (f16*)(ws + off);  off += (size_t)DD * NN * sizeof(f16);
  f16* h1sT = (f16*)(ws + off); off += (size_t)DD * NN * sizeof(f16);
  float* dinv = (float*)(ws + off); off += (size_t)NN * sizeof(float);
  off = (off + 255) & ~(size_t)255;
  float* Cpart = (float*)(ws + off); off += (size_t)KSPLIT * NN * DD * sizeof(float);
  off = (off + 255) & ~(size_t)255;
  const size_t adj16_bytes = (size_t)NN * NN * sizeof(f16);
  const bool use16 = (ws_size >= off + adj16_bytes);
  f16* adj16 = (f16*)(ws + off);

  const dim3 mmGrid(NN / BM, KSPLIT);

  prep_kernel<<<NN / 256, 256, 0, stream>>>(x, degree, xsT, dinv);
  if (use16) {
    mm_kernel<false, true><<<mmGrid, 256, 0, stream>>>(adj, nullptr, adj16, xsT, Cpart);
    epi_kernel<true><<<NN / BM, 256, 0, stream>>>(Cpart, dinv, W0, b0, nullptr, nullptr,
                                                  nullptr, h1sT, nullptr);
    mm_kernel<true, false><<<mmGrid, 256, 0, stream>>>(nullptr, adj16, nullptr, h1sT, Cpart);
    epi_kernel<false><<<NN / BM, 256, 0, stream>>>(Cpart, dinv, W1, b1, x, gamma, beta,
                                                   nullptr, out);
  } else {
    mm_kernel<false, false><<<mmGrid, 256, 0, stream>>>(adj, nullptr, nullptr, xsT, Cpart);
    epi_kernel<true><<<NN / BM, 256, 0, stream>>>(Cpart, dinv, W0, b0, nullptr, nullptr,
                                                  nullptr, h1sT, nullptr);
    mm_kernel<false, false><<<mmGrid, 256, 0, stream>>>(adj, nullptr, nullptr, h1sT, Cpart);
    epi_kernel<false><<<NN / BM, 256, 0, stream>>>(Cpart, dinv, W1, b1, x, gamma, beta,
                                                   nullptr, out);
  }
}

// Round 4
// 587.619 us; speedup vs baseline: 1.1079x; 1.0468x over previous
//
#include <hip/hip_runtime.h>

#define NN 8192
#define DD 64
#define BM 32
#define KSPLIT 8
#define KCHUNK (NN / KSPLIT)  // 1024 k per block

typedef _Float16 f16;
typedef _Float16 f16x8 __attribute__((ext_vector_type(8)));
typedef float f32x4 __attribute__((ext_vector_type(4)));

// ---------------------------------------------------------------------------
// prep: dinv[i] = rsqrt(degree[i]+1); xsT[c][i] = f16(x[i][c] * dinv[i])
// ---------------------------------------------------------------------------
__global__ __launch_bounds__(256) void prep_kernel(
    const float* __restrict__ x, const float* __restrict__ degree,
    f16* __restrict__ xsT, float* __restrict__ dinv) {
  int i = blockIdx.x * blockDim.x + threadIdx.x;
  if (i >= NN) return;
  float d = rsqrtf(degree[i] + 1.0f);
  dinv[i] = d;
  const float4* xr = (const float4*)(x + (size_t)i * DD);
#pragma unroll
  for (int c4 = 0; c4 < 16; ++c4) {
    float4 v = xr[c4];
    int c = c4 * 4;
    xsT[(size_t)(c + 0) * NN + i] = (f16)(v.x * d);
    xsT[(size_t)(c + 1) * NN + i] = (f16)(v.y * d);
    xsT[(size_t)(c + 2) * NN + i] = (f16)(v.z * d);
    xsT[(size_t)(c + 3) * NN + i] = (f16)(v.w * d);
  }
}

// ---------------------------------------------------------------------------
// mm_kernel: partial C = adj[rows rg0..rg0+31][ks0..ks0+KCHUNK) @ BT^T
// grid = (NN/BM, KSPLIT); fp32 partials to Cpart[ksp][N][64].
// Explicit 2-deep software pipeline (named reg sets A/B): keeps ~4KB/wave of
// loads in flight so 24-32 waves/CU covers HBM latency (round-3 failure was
// VGPR=20 from __launch_bounds__(256,8) -> one round trip per iteration).
// ---------------------------------------------------------------------------
template <bool A16, bool WRITE16>
__global__ __launch_bounds__(256, 4) void mm_kernel(
    const float* __restrict__ adjf, const f16* __restrict__ adjh,
    f16* __restrict__ adjh_out, const f16* __restrict__ BT,
    float* __restrict__ Cpart) {
  const int tid = threadIdx.x;
  const int wv = tid >> 6;
  const int l = tid & 63;
  const int rg0 = blockIdx.x * BM;
  const int ks0 = blockIdx.y * KCHUNK;

  // wave tiling: rows 16*(wv&1) (M=16), cols 32*(wv>>1) (two 16-col frags)
  const int rowA = 16 * (wv & 1) + (l & 15);
  const int kb = 8 * (l >> 4);  // 8 contiguous k per lane
  const int colB0 = 32 * (wv >> 1);

  f32x4 acc0 = {0.f, 0.f, 0.f, 0.f};
  f32x4 acc1 = {0.f, 0.f, 0.f, 0.f};

  const size_t arow = (size_t)(rg0 + rowA) * NN + ks0 + kb;
  const f16* bp0 = BT + (size_t)(colB0 + (l & 15)) * NN + ks0 + kb;
  const f16* bp1 = bp0 + (size_t)16 * NN;

  if constexpr (A16) {
    f16x8 Aa, Ab0, Ab1, Ba, Bb0, Bb1;
    Aa = *(const f16x8*)(adjh + arow);
    Ab0 = *(const f16x8*)(bp0);
    Ab1 = *(const f16x8*)(bp1);
    Ba = *(const f16x8*)(adjh + arow + 32);
    Bb0 = *(const f16x8*)(bp0 + 32);
    Bb1 = *(const f16x8*)(bp1 + 32);
    for (int k0 = 0; k0 < KCHUNK - 64; k0 += 64) {
      acc0 = __builtin_amdgcn_mfma_f32_16x16x32_f16(Aa, Ab0, acc0, 0, 0, 0);
      acc1 = __builtin_amdgcn_mfma_f32_16x16x32_f16(Aa, Ab1, acc1, 0, 0, 0);
      Aa = *(const f16x8*)(adjh + arow + k0 + 64);
      Ab0 = *(const f16x8*)(bp0 + k0 + 64);
      Ab1 = *(const f16x8*)(bp1 + k0 + 64);
      acc0 = __builtin_amdgcn_mfma_f32_16x16x32_f16(Ba, Bb0, acc0, 0, 0, 0);
      acc1 = __builtin_amdgcn_mfma_f32_16x16x32_f16(Ba, Bb1, acc1, 0, 0, 0);
      Ba = *(const f16x8*)(adjh + arow + k0 + 96);
      Bb0 = *(const f16x8*)(bp0 + k0 + 96);
      Bb1 = *(const f16x8*)(bp1 + k0 + 96);
    }
    acc0 = __builtin_amdgcn_mfma_f32_16x16x32_f16(Aa, Ab0, acc0, 0, 0, 0);
    acc1 = __builtin_amdgcn_mfma_f32_16x16x32_f16(Aa, Ab1, acc1, 0, 0, 0);
    acc0 = __builtin_amdgcn_mfma_f32_16x16x32_f16(Ba, Bb0, acc0, 0, 0, 0);
    acc1 = __builtin_amdgcn_mfma_f32_16x16x32_f16(Ba, Bb1, acc1, 0, 0, 0);
  } else {
    const f32x4* ap = (const f32x4*)(adjf + arow);  // 32B-aligned (kb mult of 8)
    f32x4 Aa0, Aa1, Ba0, Ba1;
    f16x8 Ab0, Ab1, Bb0, Bb1;
    Aa0 = __builtin_nontemporal_load(ap + 0);
    Aa1 = __builtin_nontemporal_load(ap + 1);
    Ab0 = *(const f16x8*)(bp0);
    Ab1 = *(const f16x8*)(bp1);
    Ba0 = __builtin_nontemporal_load(ap + 8);
    Ba1 = __builtin_nontemporal_load(ap + 9);
    Bb0 = *(const f16x8*)(bp0 + 32);
    Bb1 = *(const f16x8*)(bp1 + 32);
    for (int k0 = 0; k0 < KCHUNK - 64; k0 += 64) {
      {
        f16x8 a;
        a[0] = (f16)Aa0[0]; a[1] = (f16)Aa0[1]; a[2] = (f16)Aa0[2]; a[3] = (f16)Aa0[3];
        a[4] = (f16)Aa1[0]; a[5] = (f16)Aa1[1]; a[6] = (f16)Aa1[2]; a[7] = (f16)Aa1[3];
        if constexpr (WRITE16) {
          if (wv < 2) *(f16x8*)(adjh_out + arow + k0) = a;  // each elem once
        }
        acc0 = __builtin_amdgcn_mfma_f32_16x16x32_f16(a, Ab0, acc0, 0, 0, 0);
        acc1 = __builtin_amdgcn_mfma_f32_16x16x32_f16(a, Ab1, acc1, 0, 0, 0);
      }
      Aa0 = __builtin_nontemporal_load(ap + (k0 + 64) / 4);
      Aa1 = __builtin_nontemporal_load(ap + (k0 + 64) / 4 + 1);
      Ab0 = *(const f16x8*)(bp0 + k0 + 64);
      Ab1 = *(const f16x8*)(bp1 + k0 + 64);
      {
        f16x8 a;
        a[0] = (f16)Ba0[0]; a[1] = (f16)Ba0[1]; a[2] = (f16)Ba0[2]; a[3] = (f16)Ba0[3];
        a[4] = (f16)Ba1[0]; a[5] = (f16)Ba1[1]; a[6] = (f16)Ba1[2]; a[7] = (f16)Ba1[3];
        if constexpr (WRITE16) {
          if (wv < 2) *(f16x8*)(adjh_out + arow + k0 + 32) = a;
        }
        acc0 = __builtin_amdgcn_mfma_f32_16x16x32_f16(a, Bb0, acc0, 0, 0, 0);
        acc1 = __builtin_amdgcn_mfma_f32_16x16x32_f16(a, Bb1, acc1, 0, 0, 0);
      }
      Ba0 = __builtin_nontemporal_load(ap + (k0 + 96) / 4);
      Ba1 = __builtin_nontemporal_load(ap + (k0 + 96) / 4 + 1);
      Bb0 = *(const f16x8*)(bp0 + k0 + 96);
      Bb1 = *(const f16x8*)(bp1 + k0 + 96);
    }
    {
      const int k0 = KCHUNK - 64;
      f16x8 a;
      a[0] = (f16)Aa0[0]; a[1] = (f16)Aa0[1]; a[2] = (f16)Aa0[2]; a[3] = (f16)Aa0[3];
      a[4] = (f16)Aa1[0]; a[5] = (f16)Aa1[1]; a[6] = (f16)Aa1[2]; a[7] = (f16)Aa1[3];
      if constexpr (WRITE16) {
        if (wv < 2) *(f16x8*)(adjh_out + arow + k0) = a;
      }
      acc0 = __builtin_amdgcn_mfma_f32_16x16x32_f16(a, Ab0, acc0, 0, 0, 0);
      acc1 = __builtin_amdgcn_mfma_f32_16x16x32_f16(a, Ab1, acc1, 0, 0, 0);
      f16x8 b;
      b[0] = (f16)Ba0[0]; b[1] = (f16)Ba0[1]; b[2] = (f16)Ba0[2]; b[3] = (f16)Ba0[3];
      b[4] = (f16)Ba1[0]; b[5] = (f16)Ba1[1]; b[6] = (f16)Ba1[2]; b[7] = (f16)Ba1[3];
      if constexpr (WRITE16) {
        if (wv < 2) *(f16x8*)(adjh_out + arow + k0 + 32) = b;
      }
      acc0 = __builtin_amdgcn_mfma_f32_16x16x32_f16(b, Bb0, acc0, 0, 0, 0);
      acc1 = __builtin_amdgcn_mfma_f32_16x16x32_f16(b, Bb1, acc1, 0, 0, 0);
    }
  }

  // direct partial store. C layout: col = lane&15, row = 4*(lane>>4)+reg.
  float* cp = Cpart + ((size_t)blockIdx.y * NN + rg0 + 16 * (wv & 1) + 4 * (l >> 4)) * DD
              + colB0 + (l & 15);
#pragma unroll
  for (int j = 0; j < 4; ++j) {
    cp[(size_t)j * DD] = acc0[j];
    cp[(size_t)j * DD + 16] = acc1[j];
  }
}

// ---------------------------------------------------------------------------
// epi_kernel: sum KSPLIT partials -> C[32][64]; h = dr*(C@W)+b; then
//   FIRST:  ReLU, scale by dinv, store transposed f16 (next layer's B)
//   !FIRST: + x residual, LayerNorm * gamma + beta -> out (fp32)
// ---------------------------------------------------------------------------
template <bool FIRST>
__global__ __launch_bounds__(256) void epi_kernel(
    const float* __restrict__ Cpart, const float* __restrict__ dinv,
    const float* __restrict__ W, const float* __restrict__ bias,
    const float* __restrict__ xres, const float* __restrict__ gamma,
    const float* __restrict__ beta, f16* __restrict__ h1sT,
    float* __restrict__ out) {
  __shared__ __align__(16) float Wlds[DD * DD];
  __shared__ __align__(16) float Cs[BM][DD + 1];
  __shared__ __align__(16) f16 hT[DD][BM + 2];

  const int tid = threadIdx.x;
  const int rg0 = blockIdx.x * BM;

  for (int idx = tid * 4; idx < DD * DD; idx += 1024)
    *(float4*)&Wlds[idx] = *(const float4*)&W[idx];

  // sum partials: thread owns (row r, cols c0..c0+7)
  const int r = tid >> 3;
  const int c0 = (tid & 7) * 8;
  f32x4 s0 = {0.f, 0.f, 0.f, 0.f};
  f32x4 s1 = {0.f, 0.f, 0.f, 0.f};
#pragma unroll
  for (int ksp = 0; ksp < KSPLIT; ++ksp) {
    const float* p = Cpart + ((size_t)ksp * NN + rg0 + r) * DD + c0;
    s0 += *(const f32x4*)p;
    s1 += *(const f32x4*)(p + 4);
  }
#pragma unroll
  for (int j = 0; j < 4; ++j) { Cs[r][c0 + j] = s0[j]; Cs[r][c0 + 4 + j] = s1[j]; }
  __syncthreads();

  const float dr = dinv[rg0 + r];
  float av[8];
#pragma unroll
  for (int j = 0; j < 8; ++j) av[j] = 0.f;
  for (int k = 0; k < DD; ++k) {
    float cv = Cs[r][k];
#pragma unroll
    for (int j = 0; j < 8; ++j) av[j] += cv * Wlds[k * DD + c0 + j];
  }

  if constexpr (FIRST) {
#pragma unroll
    for (int j = 0; j < 8; ++j) {
      float h = fmaxf(dr * av[j] + bias[c0 + j], 0.f);
      hT[c0 + j][r] = (f16)(h * dr);  // pre-scale for next layer's B operand
    }
    __syncthreads();
    const int col = tid >> 2;
    const int rp = (tid & 3) * 8;
    f16x8 v;
#pragma unroll
    for (int j = 0; j < 8; ++j) v[j] = hT[col][rp + j];
    *(f16x8*)(h1sT + (size_t)col * NN + rg0 + rp) = v;
  } else {
    float hv[8];
    const float* xp = xres + (size_t)(rg0 + r) * DD + c0;
    f32x4 xa = *(const f32x4*)xp;
    f32x4 xb = *(const f32x4*)(xp + 4);
#pragma unroll
    for (int j = 0; j < 4; ++j) hv[j] = dr * av[j] + bias[c0 + j] + xa[j];
#pragma unroll
    for (int j = 0; j < 4; ++j) hv[4 + j] = dr * av[4 + j] + bias[c0 + 4 + j] + xb[j];
    float s = 0.f, sq = 0.f;
#pragma unroll
    for (int j = 0; j < 8; ++j) { s += hv[j]; sq += hv[j] * hv[j]; }
    s += __shfl_xor(s, 1); s += __shfl_xor(s, 2); s += __shfl_xor(s, 4);
    sq += __shfl_xor(sq, 1); sq += __shfl_xor(sq, 2); sq += __shfl_xor(sq, 4);
    const float mean = s * (1.f / 64.f);
    const float var = sq * (1.f / 64.f) - mean * mean;
    const float rstd = rsqrtf(var + 1e-5f);
    f32x4 o0, o1;
#pragma unroll
    for (int j = 0; j < 4; ++j)
      o0[j] = (hv[j] - mean) * rstd * gamma[c0 + j] + beta[c0 + j];
#pragma unroll
    for (int j = 0; j < 4; ++j)
      o1[j] = (hv[4 + j] - mean) * rstd * gamma[c0 + 4 + j] + beta[c0 + 4 + j];
    float* op = out + (size_t)(rg0 + r) * DD + c0;
    *(f32x4*)op = o0;
    *(f32x4*)(op + 4) = o1;
  }
}

extern "C" void kernel_launch(void* const* d_in, const int* in_sizes, int n_in,
                              void* d_out, int out_size, void* d_ws, size_t ws_size,
                              hipStream_t stream) {
  (void)in_sizes; (void)n_in; (void)out_size;
  const float* x = (const float*)d_in[0];
  const float* adj = (const float*)d_in[1];
  const float* degree = (const float*)d_in[2];
  const float* W0 = (const float*)d_in[3];
  const float* b0 = (const float*)d_in[4];
  const float* W1 = (const float*)d_in[5];
  const float* b1 = (const float*)d_in[6];
  const float* gamma = (const float*)d_in[7];
  const float* beta = (const float*)d_in[8];
  float* out = (float*)d_out;

  char* ws = (char*)d_ws;
  size_t off = 0;
  f16* xsT = (f16*)(ws + off);  off += (size_t)DD * NN * sizeof(f16);
  f16* h1sT = (f16*)(ws + off); off += (size_t)DD * NN * sizeof(f16);
  float* dinv = (float*)(ws + off); off += (size_t)NN * sizeof(float);
  off = (off + 255) & ~(size_t)255;
  float* Cpart = (float*)(ws + off); off += (size_t)KSPLIT * NN * DD * sizeof(float);
  off = (off + 255) & ~(size_t)255;
  const size_t adj16_bytes = (size_t)NN * NN * sizeof(f16);
  const bool use16 = (ws_size >= off + adj16_bytes);
  f16* adj16 = (f16*)(ws + off);

  const dim3 mmGrid(NN / BM, KSPLIT);

  prep_kernel<<<NN / 256, 256, 0, stream>>>(x, degree, xsT, dinv);
  if (use16) {
    mm_kernel<false, true><<<mmGrid, 256, 0, stream>>>(adj, nullptr, adj16, xsT, Cpart);
    epi_kernel<true><<<NN / BM, 256, 0, stream>>>(Cpart, dinv, W0, b0, nullptr, nullptr,
                                                  nullptr, h1sT, nullptr);
    mm_kernel<true, false><<<mmGrid, 256, 0, stream>>>(nullptr, adj16, nullptr, h1sT, Cpart);
    epi_kernel<false><<<NN / BM, 256, 0, stream>>>(Cpart, dinv, W1, b1, x, gamma, beta,
                                                   nullptr, out);
  } else {
    mm_kernel<false, false><<<mmGrid, 256, 0, stream>>>(adj, nullptr, nullptr, xsT, Cpart);
    epi_kernel<true><<<NN / BM, 256, 0, stream>>>(Cpart, dinv, W0, b0, nullptr, nullptr,
                                                  nullptr, h1sT, nullptr);
    mm_kernel<false, false><<<mmGrid, 256, 0, stream>>>(adj, nullptr, nullptr, h1sT, Cpart);
    epi_kernel<false><<<NN / BM, 256, 0, stream>>>(Cpart, dinv, W1, b1, x, gamma, beta,
                                                   nullptr, out);
  }
}

// Round 5
// 478.558 us; speedup vs baseline: 1.3604x; 1.2279x over previous
//
#include <hip/hip_runtime.h>

#define NN 8192
#define DD 64
#define BM 32
#define BK 128
#define KSPLIT 8
#define KCHUNK (NN / KSPLIT)  // 1024 k per block
#define NT (KCHUNK / BK)      // 8 staged tiles per block

typedef _Float16 f16;
typedef _Float16 f16x8 __attribute__((ext_vector_type(8)));
typedef float f32x4 __attribute__((ext_vector_type(4)));

// async global->LDS DMA, 16B per lane; LDS dest must be linear base+lane*16
__device__ __forceinline__ void gload16(const void* g, void* l) {
  __builtin_amdgcn_global_load_lds(
      (const __attribute__((address_space(1))) void*)g,
      (__attribute__((address_space(3))) void*)l, 16, 0, 0);
}

// ---------------------------------------------------------------------------
// prep: dinv[i] = rsqrt(degree[i]+1); xsT[c][i] = f16(x[i][c] * dinv[i])
// ---------------------------------------------------------------------------
__global__ __launch_bounds__(256) void prep_kernel(
    const float* __restrict__ x, const float* __restrict__ degree,
    f16* __restrict__ xsT, float* __restrict__ dinv) {
  int i = blockIdx.x * blockDim.x + threadIdx.x;
  if (i >= NN) return;
  float d = rsqrtf(degree[i] + 1.0f);
  dinv[i] = d;
  const float4* xr = (const float4*)(x + (size_t)i * DD);
#pragma unroll
  for (int c4 = 0; c4 < 16; ++c4) {
    float4 v = xr[c4];
    int c = c4 * 4;
    xsT[(size_t)(c + 0) * NN + i] = (f16)(v.x * d);
    xsT[(size_t)(c + 1) * NN + i] = (f16)(v.y * d);
    xsT[(size_t)(c + 2) * NN + i] = (f16)(v.z * d);
    xsT[(size_t)(c + 3) * NN + i] = (f16)(v.w * d);
  }
}

// ---------------------------------------------------------------------------
// mm_kernel: partial C = adj[rg0..rg0+31][ks0..ks0+KCHUNK) @ BT^T via
// double-buffered global_load_lds staging (2-phase, one barrier/iter).
// Swizzle: 16B-granule slot = g ^ (row&7), pre-swizzled on the GLOBAL source
// (LDS dest linear, rule #21); ds_read applies the same XOR -> conflict-free.
// A16: read f16 adj copy. WRITE16: write f16 copy from the cvt'd fragments.
// ---------------------------------------------------------------------------
template <bool A16, bool WRITE16>
__global__ __launch_bounds__(256, 2) void mm_kernel(
    const float* __restrict__ adjf, const f16* __restrict__ adjh,
    f16* __restrict__ adjh_out, const f16* __restrict__ BT,
    float* __restrict__ Cpart) {
  constexpr int AELT = BM * BK;                   // A elements per buffer
  constexpr int ABYTES = AELT * (A16 ? 2 : 4);
  constexpr int BELT = DD * BK;                   // B elements per buffer
  __shared__ __align__(16) char smem[2 * ABYTES + 2 * BELT * 2];
  float* Asf = (float*)smem;                      // [2][BM*BK] (!A16)
  f16* Ash = (f16*)smem;                          // [2][BM*BK] (A16)
  f16* Bs = (f16*)(smem + 2 * ABYTES);            // [2][DD*BK]

  const int tid = threadIdx.x;
  const int wv = tid >> 6;
  const int l = tid & 63;
  const int rg0 = blockIdx.x * BM;
  const int ks0 = blockIdx.y * KCHUNK;

  // MFMA fragment coords: A row, k-quarter, B cols
  const int ra = 16 * (wv & 1) + (l & 15);
  const int q = l >> 4;        // 0..3 -> k offset 8*q
  const int m = l & 7;         // swizzle key: ra&7 == cb&7 == l&7
  const int colB0 = 32 * (wv >> 1);
  const int cb0 = colB0 + (l & 15);
  const int cb1 = colB0 + 16 + (l & 15);

  f32x4 acc0 = {0.f, 0.f, 0.f, 0.f};
  f32x4 acc1 = {0.f, 0.f, 0.f, 0.f};

  auto stage = [&](int buf, int ks) {
    if constexpr (!A16) {
      // adj fp32 tile [32][128]: 512B/row = 32 granules; wave stages 8 rows
#pragma unroll
      for (int j = 0; j < 4; ++j) {
        const int r = 8 * wv + 2 * j + (l >> 5);
        const int s = l & 31;   // LDS slot; fetch global granule s^(r&7)
        gload16(adjf + (size_t)(rg0 + r) * NN + ks + ((s ^ (r & 7)) * 4),
                Asf + buf * AELT + r * BK + s * 4);
      }
    } else {
      // adj f16 tile [32][128]: 256B/row = 16 granules; wave stages 8 rows
#pragma unroll
      for (int j = 0; j < 2; ++j) {
        const int r = 8 * wv + 4 * j + (l >> 4);
        const int s = l & 15;
        gload16(adjh + (size_t)(rg0 + r) * NN + ks + ((s ^ (r & 7)) * 8),
                Ash + buf * AELT + r * BK + s * 8);
      }
    }
    // B tile [64 cols][128 k] f16: 256B/row = 16 granules; wave stages 16 rows
#pragma unroll
    for (int j = 0; j < 4; ++j) {
      const int c = 16 * wv + 4 * j + (l >> 4);
      const int s = l & 15;
      gload16(BT + (size_t)c * NN + ks + ((s ^ (c & 7)) * 8),
              Bs + buf * BELT + c * BK + s * 8);
    }
  };

  stage(0, ks0);
  __syncthreads();  // vmcnt(0) drain -> buf0 ready

  for (int t = 0; t < NT; ++t) {
    const int cur = t & 1;
    if (t + 1 < NT) stage(cur ^ 1, ks0 + (t + 1) * BK);  // overlaps compute

#pragma unroll
    for (int kk = 0; kk < BK; kk += 32) {
      f16x8 a;
      if constexpr (!A16) {
        const int g0 = (kk >> 2) + 2 * q;   // fp32 granule (4 floats)
        f32x4 va = *(const f32x4*)(Asf + cur * AELT + ra * BK + (g0 ^ m) * 4);
        f32x4 vb = *(const f32x4*)(Asf + cur * AELT + ra * BK + ((g0 + 1) ^ m) * 4);
        a[0] = (f16)va[0]; a[1] = (f16)va[1]; a[2] = (f16)va[2]; a[3] = (f16)va[3];
        a[4] = (f16)vb[0]; a[5] = (f16)vb[1]; a[6] = (f16)vb[2]; a[7] = (f16)vb[3];
        if constexpr (WRITE16) {
          if (wv < 2)  // each (row,k) once
            *(f16x8*)(adjh_out + (size_t)(rg0 + ra) * NN + ks0 + t * BK + kk + 8 * q) = a;
        }
      } else {
        const int g = (kk >> 3) + q;        // f16 granule (8 halves)
        a = *(const f16x8*)(Ash + cur * AELT + ra * BK + (g ^ m) * 8);
      }
      const int gb = (kk >> 3) + q;
      f16x8 b0 = *(const f16x8*)(Bs + cur * BELT + cb0 * BK + (gb ^ m) * 8);
      f16x8 b1 = *(const f16x8*)(Bs + cur * BELT + cb1 * BK + (gb ^ m) * 8);
      acc0 = __builtin_amdgcn_mfma_f32_16x16x32_f16(a, b0, acc0, 0, 0, 0);
      acc1 = __builtin_amdgcn_mfma_f32_16x16x32_f16(a, b1, acc1, 0, 0, 0);
    }
    __syncthreads();  // vmcnt(0): next buf staged; all reads of cur done
  }

  // partial store. C layout: col = lane&15, row = 4*(lane>>4)+reg (HW-verified)
  float* cp = Cpart + ((size_t)blockIdx.y * NN + rg0 + 16 * (wv & 1) + 4 * (l >> 4)) * DD
              + colB0 + (l & 15);
#pragma unroll
  for (int j = 0; j < 4; ++j) {
    cp[(size_t)j * DD] = acc0[j];
    cp[(size_t)j * DD + 16] = acc1[j];
  }
}

// ---------------------------------------------------------------------------
// epi_kernel: sum KSPLIT partials -> C[32][64]; h = dr*(C@W)+b; then
//   FIRST:  ReLU, scale by dinv, store transposed f16 (next layer's B)
//   !FIRST: + x residual, LayerNorm * gamma + beta -> out (fp32)
// ---------------------------------------------------------------------------
template <bool FIRST>
__global__ __launch_bounds__(256) void epi_kernel(
    const float* __restrict__ Cpart, const float* __restrict__ dinv,
    const float* __restrict__ W, const float* __restrict__ bias,
    const float* __restrict__ xres, const float* __restrict__ gamma,
    const float* __restrict__ beta, f16* __restrict__ h1sT,
    float* __restrict__ out) {
  __shared__ __align__(16) float Wlds[DD * DD];
  __shared__ __align__(16) float Cs[BM][DD + 1];
  __shared__ __align__(16) f16 hT[DD][BM + 2];

  const int tid = threadIdx.x;
  const int rg0 = blockIdx.x * BM;

  for (int idx = tid * 4; idx < DD * DD; idx += 1024)
    *(float4*)&Wlds[idx] = *(const float4*)&W[idx];

  const int r = tid >> 3;
  const int c0 = (tid & 7) * 8;
  f32x4 s0 = {0.f, 0.f, 0.f, 0.f};
  f32x4 s1 = {0.f, 0.f, 0.f, 0.f};
#pragma unroll
  for (int ksp = 0; ksp < KSPLIT; ++ksp) {
    const float* p = Cpart + ((size_t)ksp * NN + rg0 + r) * DD + c0;
    s0 += *(const f32x4*)p;
    s1 += *(const f32x4*)(p + 4);
  }
#pragma unroll
  for (int j = 0; j < 4; ++j) { Cs[r][c0 + j] = s0[j]; Cs[r][c0 + 4 + j] = s1[j]; }
  __syncthreads();

  const float dr = dinv[rg0 + r];
  float av[8];
#pragma unroll
  for (int j = 0; j < 8; ++j) av[j] = 0.f;
  for (int k = 0; k < DD; ++k) {
    float cv = Cs[r][k];
#pragma unroll
    for (int j = 0; j < 8; ++j) av[j] += cv * Wlds[k * DD + c0 + j];
  }

  if constexpr (FIRST) {
#pragma unroll
    for (int j = 0; j < 8; ++j) {
      float h = fmaxf(dr * av[j] + bias[c0 + j], 0.f);
      hT[c0 + j][r] = (f16)(h * dr);  // pre-scale for next layer's B operand
    }
    __syncthreads();
    const int col = tid >> 2;
    const int rp = (tid & 3) * 8;
    f16x8 v;
#pragma unroll
    for (int j = 0; j < 8; ++j) v[j] = hT[col][rp + j];
    *(f16x8*)(h1sT + (size_t)col * NN + rg0 + rp) = v;
  } else {
    float hv[8];
    const float* xp = xres + (size_t)(rg0 + r) * DD + c0;
    f32x4 xa = *(const f32x4*)xp;
    f32x4 xb = *(const f32x4*)(xp + 4);
#pragma unroll
    for (int j = 0; j < 4; ++j) hv[j] = dr * av[j] + bias[c0 + j] + xa[j];
#pragma unroll
    for (int j = 0; j < 4; ++j) hv[4 + j] = dr * av[4 + j] + bias[c0 + 4 + j] + xb[j];
    float s = 0.f, sq = 0.f;
#pragma unroll
    for (int j = 0; j < 8; ++j) { s += hv[j]; sq += hv[j] * hv[j]; }
    s += __shfl_xor(s, 1); s += __shfl_xor(s, 2); s += __shfl_xor(s, 4);
    sq += __shfl_xor(sq, 1); sq += __shfl_xor(sq, 2); sq += __shfl_xor(sq, 4);
    const float mean = s * (1.f / 64.f);
    const float var = sq * (1.f / 64.f) - mean * mean;
    const float rstd = rsqrtf(var + 1e-5f);
    f32x4 o0, o1;
#pragma unroll
    for (int j = 0; j < 4; ++j)
      o0[j] = (hv[j] - mean) * rstd * gamma[c0 + j] + beta[c0 + j];
#pragma unroll
    for (int j = 0; j < 4; ++j)
      o1[j] = (hv[4 + j] - mean) * rstd * gamma[c0 + 4 + j] + beta[c0 + 4 + j];
    float* op = out + (size_t)(rg0 + r) * DD + c0;
    *(f32x4*)op = o0;
    *(f32x4*)(op + 4) = o1;
  }
}

extern "C" void kernel_launch(void* const* d_in, const int* in_sizes, int n_in,
                              void* d_out, int out_size, void* d_ws, size_t ws_size,
                              hipStream_t stream) {
  (void)in_sizes; (void)n_in; (void)out_size;
  const float* x = (const float*)d_in[0];
  const float* adj = (const float*)d_in[1];
  const float* degree = (const float*)d_in[2];
  const float* W0 = (const float*)d_in[3];
  const float* b0 = (const float*)d_in[4];
  const float* W1 = (const float*)d_in[5];
  const float* b1 = (const float*)d_in[6];
  const float* gamma = (const float*)d_in[7];
  const float* beta = (const float*)d_in[8];
  float* out = (float*)d_out;

  char* ws = (char*)d_ws;
  size_t off = 0;
  f16* xsT = (f16*)(ws + off);  off += (size_t)DD * NN * sizeof(f16);
  f16* h1sT = (f16*)(ws + off); off += (size_t)DD * NN * sizeof(f16);
  float* dinv = (float*)(ws + off); off += (size_t)NN * sizeof(float);
  off = (off + 255) & ~(size_t)255;
  float* Cpart = (float*)(ws + off); off += (size_t)KSPLIT * NN * DD * sizeof(float);
  off = (off + 255) & ~(size_t)255;
  const size_t adj16_bytes = (size_t)NN * NN * sizeof(f16);
  const bool use16 = (ws_size >= off + adj16_bytes);
  f16* adj16 = (f16*)(ws + off);

  const dim3 mmGrid(NN / BM, KSPLIT);

  prep_kernel<<<NN / 256, 256, 0, stream>>>(x, degree, xsT, dinv);
  if (use16) {
    mm_kernel<false, true><<<mmGrid, 256, 0, stream>>>(adj, nullptr, adj16, xsT, Cpart);
    epi_kernel<true><<<NN / BM, 256, 0, stream>>>(Cpart, dinv, W0, b0, nullptr, nullptr,
                                                  nullptr, h1sT, nullptr);
    mm_kernel<true, false><<<mmGrid, 256, 0, stream>>>(nullptr, adj16, nullptr, h1sT, Cpart);
    epi_kernel<false><<<NN / BM, 256, 0, stream>>>(Cpart, dinv, W1, b1, x, gamma, beta,
                                                   nullptr, out);
  } else {
    mm_kernel<false, false><<<mmGrid, 256, 0, stream>>>(adj, nullptr, nullptr, xsT, Cpart);
    epi_kernel<true><<<NN / BM, 256, 0, stream>>>(Cpart, dinv, W0, b0, nullptr, nullptr,
                                                  nullptr, h1sT, nullptr);
    mm_kernel<false, false><<<mmGrid, 256, 0, stream>>>(adj, nullptr, nullptr, h1sT, Cpart);
    epi_kernel<false><<<NN / BM, 256, 0, stream>>>(Cpart, dinv, W1, b1, x, gamma, beta,
                                                   nullptr, out);
  }
}

// Round 6
// 449.676 us; speedup vs baseline: 1.4478x; 1.0642x over previous
//
#include <hip/hip_runtime.h>

#define NN 8192
#define DD 64
#define BM 32
#define BK 128
#define KSPLIT 8
#define KCHUNK (NN / KSPLIT)  // 1024 k per block
#define NT (KCHUNK / BK)      // 8 staged tiles per block

typedef _Float16 f16;
typedef _Float16 f16x8 __attribute__((ext_vector_type(8)));
typedef float f32x4 __attribute__((ext_vector_type(4)));

// counted vmcnt wait (T4): immediate literal, "memory" clobber orders LDS reads
#define WAITVM(N) asm volatile("s_waitcnt vmcnt(" #N ")" ::: "memory")

// async global->LDS DMA, 16B/lane; wave's 64 LDS addrs must be base + lane*16
__device__ __forceinline__ void gload16(const void* g, void* l) {
  __builtin_amdgcn_global_load_lds(
      (const __attribute__((address_space(1))) void*)g,
      (__attribute__((address_space(3))) void*)l, 16, 0, 0);
}

// ---------------------------------------------------------------------------
// prep: dinv[i] = rsqrt(degree[i]+1); xsT[c][i] = f16(x[i][c] * dinv[i])
// ---------------------------------------------------------------------------
__global__ __launch_bounds__(256) void prep_kernel(
    const float* __restrict__ x, const float* __restrict__ degree,
    f16* __restrict__ xsT, float* __restrict__ dinv) {
  int i = blockIdx.x * blockDim.x + threadIdx.x;
  if (i >= NN) return;
  float d = rsqrtf(degree[i] + 1.0f);
  dinv[i] = d;
  const float4* xr = (const float4*)(x + (size_t)i * DD);
#pragma unroll
  for (int c4 = 0; c4 < 16; ++c4) {
    float4 v = xr[c4];
    int c = c4 * 4;
    xsT[(size_t)(c + 0) * NN + i] = (f16)(v.x * d);
    xsT[(size_t)(c + 1) * NN + i] = (f16)(v.y * d);
    xsT[(size_t)(c + 2) * NN + i] = (f16)(v.z * d);
    xsT[(size_t)(c + 3) * NN + i] = (f16)(v.w * d);
  }
}

// ---------------------------------------------------------------------------
// cvt: pure streaming fp32 adj -> f16 copy (proven ~6.5 TB/s regime).
// nontemporal loads: fp32 adj is never read again; keep adj16 in L3.
// ---------------------------------------------------------------------------
__global__ __launch_bounds__(256) void cvt_kernel(
    const float* __restrict__ adjf, f16* __restrict__ adjh) {
  const size_t stride = (size_t)gridDim.x * blockDim.x;
  size_t idx = (size_t)blockIdx.x * blockDim.x + threadIdx.x;
  const size_t nvec = (size_t)NN * NN / 8;
  for (; idx < nvec; idx += stride) {
    const f32x4* p = (const f32x4*)(adjf + idx * 8);
    f32x4 a = __builtin_nontemporal_load(p);
    f32x4 b = __builtin_nontemporal_load(p + 1);
    f16x8 h;
    h[0] = (f16)a[0]; h[1] = (f16)a[1]; h[2] = (f16)a[2]; h[3] = (f16)a[3];
    h[4] = (f16)b[0]; h[5] = (f16)b[1]; h[6] = (f16)b[2]; h[7] = (f16)b[3];
    *(f16x8*)(adjh + idx * 8) = h;
  }
}

// ---------------------------------------------------------------------------
// mm_kernel: partial C = adj[rg0..rg0+31][ks0..+KCHUNK) @ BT^T.
// Triple-buffered LDS staging via global_load_lds with COUNTED vmcnt (T3+T4):
//   [wait vmcnt(stage-worth) ; s_barrier ; issue stage(t+2) ; compute(t)]
// keeps 2 stages (48KB/block) in flight across barriers; never drains to 0
// until the final tile. Swizzle: LDS slot s holds global granule s^(row&7)
// (pre-swizzled global source, linear LDS dest — rule #21).
// A16=false fallback stages fp32 adj directly (only if ws too small).
// ---------------------------------------------------------------------------
template <bool A16>
__global__ __launch_bounds__(256, A16 ? 2 : 1) void mm_kernel(
    const void* __restrict__ adjv, const f16* __restrict__ BT,
    float* __restrict__ Cpart) {
  constexpr int AELT = BM * BK;                    // A elements per buffer
  constexpr int ABYTES = AELT * (A16 ? 2 : 4);
  constexpr int BELT = DD * BK;                    // B elements per buffer
  __shared__ __align__(16) char smem[3 * ABYTES + 3 * BELT * 2];
  f16* Ash = (f16*)smem;
  float* Asf = (float*)smem;
  f16* Bs = (f16*)(smem + 3 * ABYTES);

  const f16* adjh = (const f16*)adjv;
  const float* adjf = (const float*)adjv;

  const int tid = threadIdx.x;
  const int wv = tid >> 6;
  const int l = tid & 63;
  const int rg0 = blockIdx.x * BM;
  const int ks0 = blockIdx.y * KCHUNK;

  // MFMA fragment coords (16x16x32): A row, k-quarter q, B cols
  const int ra = 16 * (wv & 1) + (l & 15);
  const int q = l >> 4;
  const int m = l & 7;                 // == ra&7 == cb0&7 == cb1&7
  const int colB0 = 32 * (wv >> 1);
  const int cb0 = colB0 + (l & 15);
  const int cb1 = cb0 + 16;

  f32x4 acc0 = {0.f, 0.f, 0.f, 0.f};
  f32x4 acc1 = {0.f, 0.f, 0.f, 0.f};

  auto stage = [&](int buf, int t) {
    const int ks = ks0 + t * BK;
    if constexpr (A16) {
      // A f16 [32][128]: 256B/row=16 granules; instr = 4 rows; 2 instr/wave
#pragma unroll
      for (int j = 0; j < 2; ++j) {
        const int r = 8 * wv + 4 * j + (l >> 4);
        const int s = l & 15;
        gload16(adjh + (size_t)(rg0 + r) * NN + ks + ((s ^ (r & 7)) * 8),
                Ash + buf * AELT + r * BK + s * 8);
      }
    } else {
      // A fp32 [32][128]: 512B/row=32 granules; instr = 2 rows; 4 instr/wave
#pragma unroll
      for (int j = 0; j < 4; ++j) {
        const int r = 8 * wv + 2 * j + (l >> 5);
        const int s = l & 31;
        gload16(adjf + (size_t)(rg0 + r) * NN + ks + ((s ^ (r & 7)) * 4),
                Asf + buf * AELT + r * BK + s * 4);
      }
    }
    // B f16 [64 cols][128]: 16 granules/col-row; 4 instr/wave
#pragma unroll
    for (int j = 0; j < 4; ++j) {
      const int c = 16 * wv + 4 * j + (l >> 4);
      const int s = l & 15;
      gload16(BT + (size_t)c * NN + ks + ((s ^ (c & 7)) * 8),
              Bs + buf * BELT + c * BK + s * 8);
    }
  };

  stage(0, 0);
  stage(1, 1);

#pragma unroll
  for (int t = 0; t < NT; ++t) {
    // wait for stage(t) only: leave stage(t+1)'s loads in flight
    if (t < NT - 1) {
      if constexpr (A16) WAITVM(6); else WAITVM(8);
    } else {
      WAITVM(0);
    }
    __builtin_amdgcn_s_barrier();   // all waves: buf t%3 fully staged;
                                    // also: all waves done computing t-1
    if (t + 2 < NT) stage((t + 2) % 3, t + 2);  // overlaps compute(t)

    const int cur = t % 3;
#pragma unroll
    for (int kk = 0; kk < BK; kk += 32) {
      f16x8 a;
      if constexpr (A16) {
        const int g = (kk >> 3) + q;
        a = *(const f16x8*)(Ash + cur * AELT + ra * BK + ((g ^ m) * 8));
      } else {
        const int g0 = (kk >> 2) + 2 * q;
        f32x4 va = *(const f32x4*)(Asf + cur * AELT + ra * BK + ((g0 ^ m) * 4));
        f32x4 vb = *(const f32x4*)(Asf + cur * AELT + ra * BK + (((g0 + 1) ^ m) * 4));
        a[0] = (f16)va[0]; a[1] = (f16)va[1]; a[2] = (f16)va[2]; a[3] = (f16)va[3];
        a[4] = (f16)vb[0]; a[5] = (f16)vb[1]; a[6] = (f16)vb[2]; a[7] = (f16)vb[3];
      }
      const int gb = (kk >> 3) + q;
      f16x8 b0 = *(const f16x8*)(Bs + cur * BELT + cb0 * BK + ((gb ^ m) * 8));
      f16x8 b1 = *(const f16x8*)(Bs + cur * BELT + cb1 * BK + ((gb ^ m) * 8));
      acc0 = __builtin_amdgcn_mfma_f32_16x16x32_f16(a, b0, acc0, 0, 0, 0);
      acc1 = __builtin_amdgcn_mfma_f32_16x16x32_f16(a, b1, acc1, 0, 0, 0);
    }
  }

  // partial store. C layout: col = lane&15, row = 4*(lane>>4)+reg (HW-verified)
  float* cp = Cpart + ((size_t)blockIdx.y * NN + rg0 + 16 * (wv & 1) + 4 * (l >> 4)) * DD
              + colB0 + (l & 15);
#pragma unroll
  for (int j = 0; j < 4; ++j) {
    cp[(size_t)j * DD] = acc0[j];
    cp[(size_t)j * DD + 16] = acc1[j];
  }
}

// ---------------------------------------------------------------------------
// epi_kernel: sum KSPLIT partials -> C[32][64]; h = dr*(C@W)+b; then
//   FIRST:  ReLU, scale by dinv, store transposed f16 (next layer's B)
//   !FIRST: + x residual, LayerNorm * gamma + beta -> out (fp32)
// ---------------------------------------------------------------------------
template <bool FIRST>
__global__ __launch_bounds__(256) void epi_kernel(
    const float* __restrict__ Cpart, const float* __restrict__ dinv,
    const float* __restrict__ W, const float* __restrict__ bias,
    const float* __restrict__ xres, const float* __restrict__ gamma,
    const float* __restrict__ beta, f16* __restrict__ h1sT,
    float* __restrict__ out) {
  __shared__ __align__(16) float Wlds[DD * DD];
  __shared__ __align__(16) float Cs[BM][DD + 1];
  __shared__ __align__(16) f16 hT[DD][BM + 2];

  const int tid = threadIdx.x;
  const int rg0 = blockIdx.x * BM;

  for (int idx = tid * 4; idx < DD * DD; idx += 1024)
    *(float4*)&Wlds[idx] = *(const float4*)&W[idx];

  const int r = tid >> 3;
  const int c0 = (tid & 7) * 8;
  f32x4 s0 = {0.f, 0.f, 0.f, 0.f};
  f32x4 s1 = {0.f, 0.f, 0.f, 0.f};
#pragma unroll
  for (int ksp = 0; ksp < KSPLIT; ++ksp) {
    const float* p = Cpart + ((size_t)ksp * NN + rg0 + r) * DD + c0;
    s0 += *(const f32x4*)p;
    s1 += *(const f32x4*)(p + 4);
  }
#pragma unroll
  for (int j = 0; j < 4; ++j) { Cs[r][c0 + j] = s0[j]; Cs[r][c0 + 4 + j] = s1[j]; }
  __syncthreads();

  const float dr = dinv[rg0 + r];
  float av[8];
#pragma unroll
  for (int j = 0; j < 8; ++j) av[j] = 0.f;
  for (int k = 0; k < DD; ++k) {
    float cv = Cs[r][k];
#pragma unroll
    for (int j = 0; j < 8; ++j) av[j] += cv * Wlds[k * DD + c0 + j];
  }

  if constexpr (FIRST) {
#pragma unroll
    for (int j = 0; j < 8; ++j) {
      float h = fmaxf(dr * av[j] + bias[c0 + j], 0.f);
      hT[c0 + j][r] = (f16)(h * dr);  // pre-scale for next layer's B operand
    }
    __syncthreads();
    const int col = tid >> 2;
    const int rp = (tid & 3) * 8;
    f16x8 v;
#pragma unroll
    for (int j = 0; j < 8; ++j) v[j] = hT[col][rp + j];
    *(f16x8*)(h1sT + (size_t)col * NN + rg0 + rp) = v;
  } else {
    float hv[8];
    const float* xp = xres + (size_t)(rg0 + r) * DD + c0;
    f32x4 xa = *(const f32x4*)xp;
    f32x4 xb = *(const f32x4*)(xp + 4);
#pragma unroll
    for (int j = 0; j < 4; ++j) hv[j] = dr * av[j] + bias[c0 + j] + xa[j];
#pragma unroll
    for (int j = 0; j < 4; ++j) hv[4 + j] = dr * av[4 + j] + bias[c0 + 4 + j] + xb[j];
    float s = 0.f, sq = 0.f;
#pragma unroll
    for (int j = 0; j < 8; ++j) { s += hv[j]; sq += hv[j] * hv[j]; }
    s += __shfl_xor(s, 1); s += __shfl_xor(s, 2); s += __shfl_xor(s, 4);
    sq += __shfl_xor(sq, 1); sq += __shfl_xor(sq, 2); sq += __shfl_xor(sq, 4);
    const float mean = s * (1.f / 64.f);
    const float var = sq * (1.f / 64.f) - mean * mean;
    const float rstd = rsqrtf(var + 1e-5f);
    f32x4 o0, o1;
#pragma unroll
    for (int j = 0; j < 4; ++j)
      o0[j] = (hv[j] - mean) * rstd * gamma[c0 + j] + beta[c0 + j];
#pragma unroll
    for (int j = 0; j < 4; ++j)
      o1[j] = (hv[4 + j] - mean) * rstd * gamma[c0 + 4 + j] + beta[c0 + 4 + j];
    float* op = out + (size_t)(rg0 + r) * DD + c0;
    *(f32x4*)op = o0;
    *(f32x4*)(op + 4) = o1;
  }
}

extern "C" void kernel_launch(void* const* d_in, const int* in_sizes, int n_in,
                              void* d_out, int out_size, void* d_ws, size_t ws_size,
                              hipStream_t stream) {
  (void)in_sizes; (void)n_in; (void)out_size;
  const float* x = (const float*)d_in[0];
  const float* adj = (const float*)d_in[1];
  const float* degree = (const float*)d_in[2];
  const float* W0 = (const float*)d_in[3];
  const float* b0 = (const float*)d_in[4];
  const float* W1 = (const float*)d_in[5];
  const float* b1 = (const float*)d_in[6];
  const float* gamma = (const float*)d_in[7];
  const float* beta = (const float*)d_in[8];
  float* out = (float*)d_out;

  char* ws = (char*)d_ws;
  size_t off = 0;
  f16* xsT = (f16*)(ws + off);  off += (size_t)DD * NN * sizeof(f16);
  f16* h1sT = (f16*)(ws + off); off += (size_t)DD * NN * sizeof(f16);
  float* dinv = (float*)(ws + off); off += (size_t)NN * sizeof(float);
  off = (off + 255) & ~(size_t)255;
  float* Cpart = (float*)(ws + off); off += (size_t)KSPLIT * NN * DD * sizeof(float);
  off = (off + 255) & ~(size_t)255;
  const size_t adj16_bytes = (size_t)NN * NN * sizeof(f16);
  const bool use16 = (ws_size >= off + adj16_bytes);
  f16* adj16 = (f16*)(ws + off);

  const dim3 mmGrid(NN / BM, KSPLIT);

  prep_kernel<<<NN / 256, 256, 0, stream>>>(x, degree, xsT, dinv);
  if (use16) {
    cvt_kernel<<<2048, 256, 0, stream>>>(adj, adj16);
    mm_kernel<true><<<mmGrid, 256, 0, stream>>>(adj16, xsT, Cpart);
    epi_kernel<true><<<NN / BM, 256, 0, stream>>>(Cpart, dinv, W0, b0, nullptr, nullptr,
                                                  nullptr, h1sT, nullptr);
    mm_kernel<true><<<mmGrid, 256, 0, stream>>>(adj16, h1sT, Cpart);
    epi_kernel<false><<<NN / BM, 256, 0, stream>>>(Cpart, dinv, W1, b1, x, gamma, beta,
                                                   nullptr, out);
  } else {
    mm_kernel<false><<<mmGrid, 256, 0, stream>>>(adj, xsT, Cpart);
    epi_kernel<true><<<NN / BM, 256, 0, stream>>>(Cpart, dinv, W0, b0, nullptr, nullptr,
                                                  nullptr, h1sT, nullptr);
    mm_kernel<false><<<mmGrid, 256, 0, stream>>>(adj, h1sT, Cpart);
    epi_kernel<false><<<NN / BM, 256, 0, stream>>>(Cpart, dinv, W1, b1, x, gamma, beta,
                                                   nullptr, out);
  }
}